// Round 14
// baseline (337.946 us; speedup 1.0000x reference)
//
#include <hip/hip_runtime.h>
#include <hip/hip_cooperative_groups.h>

namespace cg = cooperative_groups;

#define OUT_COLS 448
#define OUT_STRIDE (OUT_COLS * 32)   // 14336 floats per batch row
#define NTREES 128
#define TDEPTH 6
#define NT (NTREES * TDEPTH)         // 768 rows per layer
#define DD 32
#define BB 64
#define PADW 64                      // padded compacted width for fs output

template <int CTRL, int RMASK = 0xf, bool BC = true>
__device__ __forceinline__ float dppf(float v) {
    return __int_as_float(
        __builtin_amdgcn_update_dpp(0, __float_as_int(v), CTRL, RMASK, 0xf, BC));
}

__device__ __forceinline__ float wred64(float x) {
    x += dppf<0x111>(x);
    x += dppf<0x112>(x);
    x += dppf<0x114>(x);
    x += dppf<0x118>(x);
    x += __int_as_float(__builtin_amdgcn_update_dpp(0, __float_as_int(x), 0x142, 0xa, 0xf, false)); // row_bcast15
    x += __int_as_float(__builtin_amdgcn_update_dpp(0, __float_as_int(x), 0x143, 0xc, 0xf, false)); // row_bcast31
    return __int_as_float(__builtin_amdgcn_readlane(__float_as_int(x), 63));
}

// ---------------------------------------------------------------- fs sparsemax via Michelot (one wave/row)
template <int J>
__device__ __forceinline__ void fs_row(const float* __restrict__ zr, int lane,
                                       float2* __restrict__ fjv, int* __restrict__ fcnt_p) {
    constexpr int T = J / 64;
    float z[T];
    #pragma unroll
    for (int t = 0; t < T; ++t) z[t] = zr[t * 64 + lane];
    float sp = 0.f;
    #pragma unroll
    for (int t = 0; t < T; ++t) sp += z[t];
    float k = (float)J;
    float tau = (wred64(sp) - 1.f) / k;
    #pragma unroll 1
    for (int it = 0; it < 64; ++it) {
        float s2 = 0.f, c2 = 0.f;
        #pragma unroll
        for (int t = 0; t < T; ++t) {
            bool g = z[t] > tau;
            s2 += g ? z[t] : 0.f;
            c2 += g ? 1.f : 0.f;
        }
        float S2 = wred64(s2);
        float K2 = wred64(c2);
        if (K2 == k) break;
        k = K2;
        tau = (S2 - 1.f) / K2;
    }
    unsigned long long below = (1ull << lane) - 1ull;
    int base = 0;
    #pragma unroll
    for (int t = 0; t < T; ++t) {
        bool sup = z[t] > tau;
        unsigned long long m = __ballot(sup);
        int pos = base + __popcll(m & below);
        if (sup && pos < PADW)
            fjv[pos] = make_float2(__int_as_float((t * 64 + lane) * 128), z[t] - tau);
        base += __popcll(m);
    }
    int cnt = base < PADW ? base : PADW;
    for (int i = cnt + lane; i < PADW; i += 64)
        fjv[i] = make_float2(__int_as_float(0), 0.f);
    if (lane == 0) *fcnt_p = cnt;
}

template <int S>
__device__ __forceinline__ void bstep(float* a, int lane) {
    constexpr int half = 16 >> S;
    bool up = ((lane >> S) & 1) != 0;
    #pragma unroll
    for (int q = 0; q < half; ++q) {
        float send = up ? a[q] : a[half + q];
        float recv;
        if constexpr (S == 0)      recv = dppf<0xB1>(send);
        else if constexpr (S == 1) recv = dppf<0x4E>(send);
        else recv = __int_as_float(__builtin_amdgcn_ds_swizzle(
                        __float_as_int(send), ((1 << S) << 10) | 0x1F));
        float keep = up ? a[half + q] : a[q];
        a[q] = keep + recv;
    }
}

// ---------------------------------------------------------------- es wave-task (global id w in [0, 6912))
__device__ __forceinline__ void es_task(int w, int lane,
                                        const float* __restrict__ e0,
                                        const float* __restrict__ e1,
                                        const float* __restrict__ e2,
                                        float* __restrict__ part) {
    const float* esl; int row, chunk, J; size_t grow;
    if (w < NT)          { esl = e0; row = w; chunk = 0; J = 64; grow = (size_t)row; }
    else if (w < 4 * NT) { int q = w - NT; esl = e1; row = q / 3; chunk = q - row * 3; J = 192; grow = (size_t)(NT + row); }
    else                 { int q = w - 4 * NT; esl = e2; row = q / 5; chunk = q - row * 5; J = 320; grow = (size_t)(2 * NT + row); }

    const float4* zp4 = (const float4*)(esl + ((size_t)row * J + chunk * 64 + lane) * 32);
    float z[32];
    #pragma unroll
    for (int i = 0; i < 8; ++i) {
        float4 v = zp4[i];
        z[4 * i] = v.x; z[4 * i + 1] = v.y; z[4 * i + 2] = v.z; z[4 * i + 3] = v.w;
    }
    float mx = z[0];
    #pragma unroll
    for (int i = 1; i < 32; ++i) mx = fmaxf(mx, z[i]);
    float tau = mx - 1.0f;
    int kprev = -1;
    #pragma unroll 1
    for (int it = 0; it < 40; ++it) {
        float s0 = 0.f, s1 = 0.f, s2 = 0.f, s3 = 0.f;
        int k0 = 0, k1 = 0, k2 = 0, k3 = 0;
        #pragma unroll
        for (int i = 0; i < 8; ++i) {
            bool g0 = z[4 * i]     > tau; s0 += g0 ? z[4 * i]     : 0.f; k0 += g0;
            bool g1 = z[4 * i + 1] > tau; s1 += g1 ? z[4 * i + 1] : 0.f; k1 += g1;
            bool g2 = z[4 * i + 2] > tau; s2 += g2 ? z[4 * i + 2] : 0.f; k2 += g2;
            bool g3 = z[4 * i + 3] > tau; s3 += g3 ? z[4 * i + 3] : 0.f; k3 += g3;
        }
        float S = (s0 + s1) + (s2 + s3);
        int k = (k0 + k1) + (k2 + k3);
        bool chg = (k != kprev);
        kprev = k;
        tau = (S - 1.0f) / (float)k;
        if (__ballot(chg) == 0ull) break;
    }
    #pragma unroll
    for (int i = 0; i < 32; ++i) z[i] = fmaxf(z[i] - tau, 0.f);
    bstep<0>(z, lane);
    bstep<1>(z, lane);
    bstep<2>(z, lane);
    bstep<3>(z, lane);
    bstep<4>(z, lane);
    z[0] += __shfl_xor(z[0], 32, 64);
    if (lane < 32) {
        int d = ((lane & 1) << 4) | ((lane & 2) << 2) | (lane & 4)
              | ((lane & 8) >> 2) | ((lane & 16) >> 4);
        part[(grow * 5 + chunk) * 32 + d] = z[0];
    }
}

// shared phase-0 wave-task dispatcher (tsk in [0, 9728))
__device__ __forceinline__ void phase0_task(int tsk, int lane,
        const float* __restrict__ x,
        const float* __restrict__ f0, const float* __restrict__ f1,
        const float* __restrict__ f2,
        const float* __restrict__ e0, const float* __restrict__ e1,
        const float* __restrict__ e2,
        float2* __restrict__ fjv, int* __restrict__ fcnt,
        float* __restrict__ part, float* __restrict__ out) {
    if (tsk < 512) {
        const float4* x4 = (const float4*)x;
        float4* o4 = (float4*)out;
        int g = tsk * 64 + lane;
        int b = g >> 9, r = g & 511;
        o4[(size_t)b * (OUT_STRIDE / 4) + r] = x4[g];
    } else if (tsk < 512 + 3 * NT) {
        int w = tsk - 512;
        if (w < NT) {
            fs_row<64>(f0 + (size_t)w * 64, lane, fjv + (size_t)w * PADW, fcnt + w);
        } else if (w < 2 * NT) {
            int r = w - NT;
            fs_row<192>(f1 + (size_t)r * 192, lane,
                        fjv + (size_t)(NT + r) * PADW, fcnt + NT + r);
        } else {
            int r = w - 2 * NT;
            fs_row<320>(f2 + (size_t)r * 320, lane,
                        fjv + (size_t)(2 * NT + r) * PADW, fcnt + 2 * NT + r);
        }
    } else {
        es_task(tsk - (512 + 3 * NT), lane, e0, e1, e2, part);
    }
}

// per-tree vectorized gather: one ds_read_b128 (2 pairs) + two float4 x loads
#define GATHER_T(sjvt, acc) {                                            \
    float4 q = (sjvt)[qi];                                               \
    float4 xA = *(const float4*)(xb16 + __float_as_int(q.x));            \
    float4 xB = *(const float4*)(xb16 + __float_as_int(q.z));            \
    acc.x = fmaf(xA.x, q.y, fmaf(xB.x, q.w, acc.x));                     \
    acc.y = fmaf(xA.y, q.y, fmaf(xB.y, q.w, acc.y));                     \
    acc.z = fmaf(xA.z, q.y, fmaf(xB.z, q.w, acc.z));                     \
    acc.w = fmaf(xA.w, q.y, fmaf(xB.w, q.w, acc.w)); }

#define REDSTEP(a, M) { a.x += __shfl_xor(a.x, M); a.y += __shfl_xor(a.y, M); \
                        a.z += __shfl_xor(a.z, M); a.w += __shfl_xor(a.w, M); }

__device__ __forceinline__ float selr(float4 v, int r) {
    float lo = (r & 1) ? v.y : v.x;
    float hi = (r & 1) ? v.w : v.z;
    return (r & 2) ? hi : lo;
}

// main body for logical block blk (0..1023) of layer L — shared by both paths
struct MainSmem {
    float4 s_jv[TDEPTH][PADW / 2];
    float2 s_resp2[DD][33];
    float  s_ess[TDEPTH][DD];
    float  s_thr[TDEPTH], s_elt[TDEPTH];
    int    s_cnt[TDEPTH];
};

__device__ __forceinline__ void main_body(MainSmem& sm, int blk, int tid,
        const float2* __restrict__ fjvL, const int* __restrict__ fcntL,
        const float* __restrict__ partL, int nch,
        const float* __restrict__ thr, const float* __restrict__ lt,
        const float* __restrict__ resp, float* __restrict__ out, int colOff) {
    int n  = blk & (NTREES - 1);
    int by = blk >> 7;

    {
        const float4* g = (const float4*)(fjvL + (size_t)n * TDEPTH * PADW);
        if (tid < 192) ((float4*)sm.s_jv)[tid] = g[tid];
    }
    {
        const float2* g = (const float2*)(resp + (size_t)n * (DD * 64));
        for (int i = tid; i < DD * 32; i += 256)
            sm.s_resp2[i >> 5][i & 31] = g[i];
    }
    if (tid < TDEPTH * DD) {
        int t = tid >> 5, d = tid & 31;
        float e = 0.f;
        #pragma unroll
        for (int c = 0; c < 5; ++c)
            if (c < nch) e += partL[((size_t)(n * TDEPTH + t) * 5 + c) * 32 + d];
        sm.s_ess[t][d] = e;
    }
    if (tid < TDEPTH) {
        int r = n * TDEPTH + tid;
        sm.s_thr[tid] = thr[r];
        sm.s_elt[tid] = expf(-lt[r]);
        sm.s_cnt[tid] = fcntL[r];
    }
    __syncthreads();

    int b   = by * 8 + (tid >> 5);
    int sub = tid & 31;
    int r   = sub >> 3;
    int dq  = sub & 7;
    const char* xb16 = (const char*)(out + (size_t)b * OUT_STRIDE) + dq * 16;

    int maxc = sm.s_cnt[0];
    #pragma unroll
    for (int t = 1; t < TDEPTH; ++t) maxc = max(maxc, sm.s_cnt[t]);
    int rounds = (maxc + 7) >> 3;

    float4 a0 = {0,0,0,0}, a1 = {0,0,0,0}, a2 = {0,0,0,0};
    float4 a3 = {0,0,0,0}, a4 = {0,0,0,0}, a5 = {0,0,0,0};
    for (int m = 0; m < rounds; ++m) {
        int qi = r + 4 * m;
        GATHER_T(sm.s_jv[0], a0);
        GATHER_T(sm.s_jv[1], a1);
        GATHER_T(sm.s_jv[2], a2);
        GATHER_T(sm.s_jv[3], a3);
        GATHER_T(sm.s_jv[4], a4);
        GATHER_T(sm.s_jv[5], a5);
    }
    REDSTEP(a0, 8);  REDSTEP(a0, 16);
    REDSTEP(a1, 8);  REDSTEP(a1, 16);
    REDSTEP(a2, 8);  REDSTEP(a2, 16);
    REDSTEP(a3, 8);  REDSTEP(a3, 16);
    REDSTEP(a4, 8);  REDSTEP(a4, 16);
    REDSTEP(a5, 8);  REDSTEP(a5, 16);

    int d = 4 * dq + r;
    float sv[TDEPTH];
    {
        float accs[TDEPTH] = { selr(a0, r), selr(a1, r), selr(a2, r),
                               selr(a3, r), selr(a4, r), selr(a5, r) };
        #pragma unroll
        for (int t = 0; t < TDEPTH; ++t) {
            float sel = accs[t] * sm.s_ess[t][d];
            float tlv = (sel - sm.s_thr[t]) * sm.s_elt[t];
            sv[t] = fminf(fmaxf(0.5f * tlv + 0.5f, 0.f), 1.f);
        }
    }
    float A[8], Bv[8];
    {
        float p0 = sv[0], p1 = 1.f - sv[0];
        float q0 = sv[1], q1 = 1.f - sv[1];
        float c0 = sv[2], c1 = 1.f - sv[2];
        A[0] = p0 * q0 * c0; A[1] = p1 * q0 * c0;
        A[2] = p0 * q1 * c0; A[3] = p1 * q1 * c0;
        A[4] = p0 * q0 * c1; A[5] = p1 * q0 * c1;
        A[6] = p0 * q1 * c1; A[7] = p1 * q1 * c1;
        float u0 = sv[3], u1 = 1.f - sv[3];
        float v0 = sv[4], v1 = 1.f - sv[4];
        float w0 = sv[5], w1 = 1.f - sv[5];
        Bv[0] = u0 * v0 * w0; Bv[1] = u1 * v0 * w0;
        Bv[2] = u0 * v1 * w0; Bv[3] = u1 * v1 * w0;
        Bv[4] = u0 * v0 * w1; Bv[5] = u1 * v0 * w1;
        Bv[6] = u0 * v1 * w1; Bv[7] = u1 * v1 * w1;
    }
    float o = 0.f;
    #pragma unroll
    for (int c2 = 0; c2 < 8; ++c2) {
        float2 r0 = sm.s_resp2[d][(8 * c2) >> 1];
        float2 r1 = sm.s_resp2[d][(8 * c2 + 2) >> 1];
        float2 r2 = sm.s_resp2[d][(8 * c2 + 4) >> 1];
        float2 r3 = sm.s_resp2[d][(8 * c2 + 6) >> 1];
        float inner = (A[0] * r0.x + A[1] * r0.y) + (A[2] * r1.x + A[3] * r1.y)
                    + (A[4] * r2.x + A[5] * r2.y) + (A[6] * r3.x + A[7] * r3.y);
        o += Bv[c2] * inner;
    }
    out[(size_t)b * OUT_STRIDE + (size_t)(colOff + n) * DD + d] = o;
}

// ---------------------------------------------------------------- path A: single cooperative kernel
__global__ __launch_bounds__(256, 4)
void fused_kernel(const float* __restrict__ x,
                  const float* __restrict__ f0, const float* __restrict__ f1,
                  const float* __restrict__ f2,
                  const float* __restrict__ e0, const float* __restrict__ e1,
                  const float* __restrict__ e2,
                  float2* __restrict__ fjv, int* __restrict__ fcnt,
                  float* __restrict__ part, float* __restrict__ out,
                  const float* __restrict__ thr0, const float* __restrict__ lt0,
                  const float* __restrict__ resp0,
                  const float* __restrict__ thr1, const float* __restrict__ lt1,
                  const float* __restrict__ resp1,
                  const float* __restrict__ thr2, const float* __restrict__ lt2,
                  const float* __restrict__ resp2) {
    cg::grid_group grid = cg::this_grid();
    int tid = threadIdx.x;
    int lane = tid & 63;
    int nWaves = gridDim.x * 4;
    int wid = blockIdx.x * 4 + (tid >> 6);

    for (int tsk = wid; tsk < 9728; tsk += nWaves)
        phase0_task(tsk, lane, x, f0, f1, f2, e0, e1, e2, fjv, fcnt, part, out);
    __threadfence();
    grid.sync();

    __shared__ MainSmem sm;
    #pragma unroll 1
    for (int L = 0; L < 3; ++L) {
        const float2* fjvL  = fjv + (size_t)L * NT * PADW;
        const int*    fcntL = fcnt + L * NT;
        const float*  partL = part + (size_t)L * NT * 5 * 32;
        const float*  thr   = (L == 0) ? thr0 : (L == 1) ? thr1 : thr2;
        const float*  lt    = (L == 0) ? lt0  : (L == 1) ? lt1  : lt2;
        const float*  resp  = (L == 0) ? resp0 : (L == 1) ? resp1 : resp2;
        int nch    = (L == 0) ? 1 : (L == 1) ? 3 : 5;
        int colOff = 64 + L * NTREES;

        for (int blk = blockIdx.x; blk < 1024; blk += gridDim.x) {
            __syncthreads();   // previous iteration readers done with LDS
            main_body(sm, blk, tid, fjvL, fcntL, partL, nch, thr, lt, resp, out, colOff);
        }
        if (L < 2) {
            __threadfence();
            grid.sync();
        }
    }
}

// ---------------------------------------------------------------- path B (fallback): round-12 kernels
__global__ __launch_bounds__(256)
void prep_kernel(const float* __restrict__ x,
                 const float* __restrict__ f0, const float* __restrict__ f1,
                 const float* __restrict__ f2,
                 const float* __restrict__ e0, const float* __restrict__ e1,
                 const float* __restrict__ e2,
                 float2* __restrict__ fjv, int* __restrict__ fcnt,
                 float* __restrict__ part, float* __restrict__ out, int esEnd) {
    int w = blockIdx.x * 4 + (threadIdx.x >> 6);
    int lane = threadIdx.x & 63;
    if (w < 512 + 3 * NT) { phase0_task(w, lane, x, f0, f1, f2, e0, e1, e2, fjv, fcnt, part, out); return; }
    w -= 512 + 3 * NT;
    if (w < esEnd) es_task(w, lane, e0, e1, e2, part);
}

__global__ __launch_bounds__(256)
void mainplus_kernel(const float2* __restrict__ fjvL, const int* __restrict__ fcnt,
                     const float* __restrict__ partL, int nch,
                     const float* __restrict__ thr, const float* __restrict__ lt,
                     const float* __restrict__ resp,
                     float* __restrict__ out, int colOff,
                     const float* __restrict__ e0, const float* __restrict__ e1,
                     const float* __restrict__ e2, float* __restrict__ partAll,
                     int nMain, int esBeg, int esEnd) {
    int tid = threadIdx.x;
    if ((int)blockIdx.x >= nMain) {
        int w = esBeg + (blockIdx.x - nMain) * 4 + (tid >> 6);
        if (w < esEnd) es_task(w, tid & 63, e0, e1, e2, partAll);
        return;
    }
    __shared__ MainSmem sm;
    main_body(sm, blockIdx.x, tid, fjvL, fcnt, partL, nch, thr, lt, resp, out, colOff);
}

// ----------------------------------------------------------------
extern "C" void kernel_launch(void* const* d_in, const int* in_sizes, int n_in,
                              void* d_out, int out_size, void* d_ws, size_t ws_size,
                              hipStream_t stream) {
    const float* x = (const float*)d_in[0];
    float* out = (float*)d_out;

    const size_t NPAD = (size_t)3 * NT * PADW;   // 147456 pairs
    char* ws = (char*)d_ws;
    float2* fjv  = (float2*)(ws);
    int*    fcnt = (int*)(ws + NPAD * 8);
    float*  part = (float*)(ws + NPAD * 8 + 16384);

    const float* f0 = (const float*)d_in[1];
    const float* f1 = (const float*)d_in[6];
    const float* f2 = (const float*)d_in[11];
    const float* e0 = (const float*)d_in[2];
    const float* e1 = (const float*)d_in[7];
    const float* e2 = (const float*)d_in[12];
    const float* thr0 = (const float*)d_in[3],  *lt0 = (const float*)d_in[4],
               * resp0 = (const float*)d_in[5];
    const float* thr1 = (const float*)d_in[8],  *lt1 = (const float*)d_in[9],
               * resp1 = (const float*)d_in[10];
    const float* thr2 = (const float*)d_in[13], *lt2 = (const float*)d_in[14],
               * resp2 = (const float*)d_in[15];

    // ---- try the single cooperative launch, grid sized from the runtime's occupancy ----
    int perCU = 0, nCU = 0;
    hipError_t eo = hipOccupancyMaxActiveBlocksPerMultiprocessor(
        &perCU, (const void*)fused_kernel, 256, 0);
    hipError_t ea = hipDeviceGetAttribute(&nCU, hipDeviceAttributeMultiprocessorCount, 0);
    bool coopOk = false;
    if (eo == hipSuccess && ea == hipSuccess && perCU > 0 && nCU > 0) {
        int grid = perCU * nCU;
        if (grid > 1024) grid = 1024;
        void* args[] = { (void*)&x, (void*)&f0, (void*)&f1, (void*)&f2,
                         (void*)&e0, (void*)&e1, (void*)&e2,
                         (void*)&fjv, (void*)&fcnt, (void*)&part, (void*)&out,
                         (void*)&thr0, (void*)&lt0, (void*)&resp0,
                         (void*)&thr1, (void*)&lt1, (void*)&resp1,
                         (void*)&thr2, (void*)&lt2, (void*)&resp2 };
        hipError_t el = hipLaunchCooperativeKernel((const void*)fused_kernel,
                                                   dim3(grid), dim3(256), args, 0, stream);
        coopOk = (el == hipSuccess);
    }
    if (coopOk) return;

    // ---- fallback: proven 3-launch overlapped path (round 12) ----
    const int ES_A = 2304, ES_B = 4608;
    prep_kernel<<<5120 / 4, 256, 0, stream>>>(
        x, f0, f1, f2, e0, e1, e2, fjv, fcnt, part, out, ES_A);

    const int nchs[3] = {1, 3, 5};
    int colOff = 64;
    for (int L = 0; L < 3; ++L) {
        const float* thr  = (L == 0) ? thr0 : (L == 1) ? thr1 : thr2;
        const float* lt   = (L == 0) ? lt0  : (L == 1) ? lt1  : lt2;
        const float* resp = (L == 0) ? resp0 : (L == 1) ? resp1 : resp2;
        int esBeg = (L == 0) ? ES_A : (L == 1) ? ES_B : 0;
        int esEnd = (L == 0) ? ES_B : (L == 1) ? 6912 : 0;
        int nEsBlocks = (esEnd - esBeg + 3) / 4;
        mainplus_kernel<<<1024 + nEsBlocks, 256, 0, stream>>>(
            fjv + (size_t)L * NT * PADW, fcnt + L * NT,
            part + (size_t)L * NT * 5 * 32, nchs[L],
            thr, lt, resp, out, colOff,
            e0, e1, e2, part, 1024, esBeg, esEnd);
        colOff += NTREES;
    }
}

// Round 15
// 62.850 us; speedup vs baseline: 5.3770x; 5.3770x over previous
//
#include <hip/hip_runtime.h>

#define OUT_COLS 448
#define OUT_STRIDE (OUT_COLS * 32)   // 14336 floats per batch row
#define NTREES 128
#define TDEPTH 6
#define NT (NTREES * TDEPTH)         // 768 rows per layer
#define DD 32
#define BB 64
#define PADW 64                      // padded compacted width for fs output

// DPP mov helper (compile-time ctrl)
template <int CTRL, int RMASK = 0xf, bool BC = true>
__device__ __forceinline__ float dppf(float v) {
    return __int_as_float(
        __builtin_amdgcn_update_dpp(0, __float_as_int(v), CTRL, RMASK, 0xf, BC));
}

// cross-lane xor helpers: xor1/xor2 are DPP quad_perm (VALU pipe), larger are ds_swizzle/shfl
__device__ __forceinline__ float swx1(float v)  { return dppf<0xB1>(v); }               // [1,0,3,2]
__device__ __forceinline__ float swx2(float v)  { return dppf<0x4E>(v); }               // [2,3,0,1]
__device__ __forceinline__ float swx4(float v)  { return __int_as_float(__builtin_amdgcn_ds_swizzle(__float_as_int(v), 0x101F)); }
__device__ __forceinline__ float swx8(float v)  { return __int_as_float(__builtin_amdgcn_ds_swizzle(__float_as_int(v), 0x201F)); }
__device__ __forceinline__ float swx16(float v) { return __int_as_float(__builtin_amdgcn_ds_swizzle(__float_as_int(v), 0x401F)); }

// full-wave (64-lane) sum, result broadcast to all lanes via readlane
__device__ __forceinline__ float wred64(float x) {
    x += dppf<0x111>(x);
    x += dppf<0x112>(x);
    x += dppf<0x114>(x);
    x += dppf<0x118>(x);
    x += __int_as_float(__builtin_amdgcn_update_dpp(0, __float_as_int(x), 0x142, 0xa, 0xf, false)); // row_bcast15
    x += __int_as_float(__builtin_amdgcn_update_dpp(0, __float_as_int(x), 0x143, 0xc, 0xf, false)); // row_bcast31
    return __int_as_float(__builtin_amdgcn_readlane(__float_as_int(x), 63));
}

// ---------------------------------------------------------------- fs sparsemax via Michelot (one wave/row)
template <int J>
__device__ __forceinline__ void fs_row(const float* __restrict__ zr, int lane,
                                       float2* __restrict__ fjv, int* __restrict__ fcnt_p) {
    constexpr int T = J / 64;
    float z[T];
    #pragma unroll
    for (int t = 0; t < T; ++t) z[t] = zr[t * 64 + lane];
    float sp = 0.f;
    #pragma unroll
    for (int t = 0; t < T; ++t) sp += z[t];
    float k = (float)J;
    float tau = (wred64(sp) - 1.f) / k;
    #pragma unroll 1
    for (int it = 0; it < 64; ++it) {
        float s2 = 0.f, c2 = 0.f;
        #pragma unroll
        for (int t = 0; t < T; ++t) {
            bool g = z[t] > tau;
            s2 += g ? z[t] : 0.f;
            c2 += g ? 1.f : 0.f;
        }
        float S2 = wred64(s2);
        float K2 = wred64(c2);
        if (K2 == k) break;
        k = K2;
        tau = (S2 - 1.f) / K2;
    }
    unsigned long long below = (1ull << lane) - 1ull;
    int base = 0;
    #pragma unroll
    for (int t = 0; t < T; ++t) {
        bool sup = z[t] > tau;
        unsigned long long m = __ballot(sup);
        int pos = base + __popcll(m & below);
        if (sup && pos < PADW)
            fjv[pos] = make_float2(__int_as_float((t * 64 + lane) * 128), z[t] - tau);
        base += __popcll(m);
    }
    int cnt = base < PADW ? base : PADW;
    for (int i = cnt + lane; i < PADW; i += 64)
        fjv[i] = make_float2(__int_as_float(0), 0.f);
    if (lane == 0) *fcnt_p = cnt;
}

// ---------------------------------------------------------------- es wave-task (global id w in [0, 6912))
// 8-lane-per-row Michelot: lane holds 4 elems; loads are FULLY coalesced (zp4[p*64+lane]).
__device__ __forceinline__ void es_task(int w, int lane,
                                        const float* __restrict__ e0,
                                        const float* __restrict__ e1,
                                        const float* __restrict__ e2,
                                        float* __restrict__ part) {
    const float* esl; int row, chunk, J; size_t grow;
    if (w < NT)          { esl = e0; row = w; chunk = 0; J = 64; grow = (size_t)row; }
    else if (w < 4 * NT) { int q = w - NT; esl = e1; row = q / 3; chunk = q - row * 3; J = 192; grow = (size_t)(NT + row); }
    else                 { int q = w - 4 * NT; esl = e2; row = q / 5; chunk = q - row * 5; J = 320; grow = (size_t)(2 * NT + row); }

    const float4* zp4 = (const float4*)(esl + ((size_t)row * J + chunk * 64) * 32);
    float4 acc = make_float4(0.f, 0.f, 0.f, 0.f);
    #pragma unroll
    for (int p = 0; p < 8; ++p) {        // pass p: rows p*8 + (lane>>3); elems d=(lane&7)*4..+3
        float4 v = zp4[p * 64 + lane];   // contiguous 1KB per wave instruction
        float mx = fmaxf(fmaxf(v.x, v.y), fmaxf(v.z, v.w));
        mx = fmaxf(mx, swx1(mx));
        mx = fmaxf(mx, swx2(mx));
        mx = fmaxf(mx, swx4(mx));
        float tau = mx - 1.0f;           // warm start (valid lower bound on tau*)
        float kprev = -1.0f;
        #pragma unroll 1
        for (int it = 0; it < 40; ++it) {
            float s  = (v.x > tau ? v.x : 0.f) + (v.y > tau ? v.y : 0.f)
                     + (v.z > tau ? v.z : 0.f) + (v.w > tau ? v.w : 0.f);
            float kc = (v.x > tau ? 1.f : 0.f) + (v.y > tau ? 1.f : 0.f)
                     + (v.z > tau ? 1.f : 0.f) + (v.w > tau ? 1.f : 0.f);
            s += swx1(s);   kc += swx1(kc);
            s += swx2(s);   kc += swx2(kc);
            s += swx4(s);   kc += swx4(kc);    // 8-lane butterfly: all lanes hold row totals
            bool chg = (kc != kprev);
            kprev = kc;
            tau = (s - 1.0f) / kc;             // idempotent once the active set is stable
            if (__ballot(chg) == 0ull) break;
        }
        acc.x += fmaxf(v.x - tau, 0.f);
        acc.y += fmaxf(v.y - tau, 0.f);
        acc.z += fmaxf(v.z - tau, 0.f);
        acc.w += fmaxf(v.w - tau, 0.f);
    }
    // column sums over the 64 rows: reduce across lane>>3 (masks 8,16,32)
    acc.x += swx8(acc.x);  acc.y += swx8(acc.y);  acc.z += swx8(acc.z);  acc.w += swx8(acc.w);
    acc.x += swx16(acc.x); acc.y += swx16(acc.y); acc.z += swx16(acc.z); acc.w += swx16(acc.w);
    acc.x += __shfl_xor(acc.x, 32, 64);
    acc.y += __shfl_xor(acc.y, 32, 64);
    acc.z += __shfl_xor(acc.z, 32, 64);
    acc.w += __shfl_xor(acc.w, 32, 64);
    if (lane < 8) {                      // lane l holds d = l*4..l*4+3
        float4* p4 = (float4*)(part + (grow * 5 + chunk) * 32);
        p4[lane] = acc;
    }
}

// ---------------------------------------------------------------- fused prep: copy_x + fs + es (R10 structure)
__global__ __launch_bounds__(256)
void prep_kernel(const float* __restrict__ x,
                 const float* __restrict__ f0, const float* __restrict__ f1,
                 const float* __restrict__ f2,
                 const float* __restrict__ e0, const float* __restrict__ e1,
                 const float* __restrict__ e2,
                 float2* __restrict__ fjv, int* __restrict__ fcnt,
                 float* __restrict__ part, float* __restrict__ out) {
    int w = blockIdx.x * 4 + (threadIdx.x >> 6);
    int lane = threadIdx.x & 63;

    if (w < 512) {                       // ---- copy x ----
        const float4* x4 = (const float4*)x;
        float4* o4 = (float4*)out;
        int g = w * 64 + lane;
        int b = g >> 9, r = g & 511;
        o4[(size_t)b * (OUT_STRIDE / 4) + r] = x4[g];
        return;
    }
    w -= 512;
    if (w < 3 * NT) {                    // ---- fs ----
        if (w < NT) {
            fs_row<64>(f0 + (size_t)w * 64, lane, fjv + (size_t)w * PADW, fcnt + w);
        } else if (w < 2 * NT) {
            int r = w - NT;
            fs_row<192>(f1 + (size_t)r * 192, lane,
                        fjv + (size_t)(NT + r) * PADW, fcnt + NT + r);
        } else {
            int r = w - 2 * NT;
            fs_row<320>(f2 + (size_t)r * 320, lane,
                        fjv + (size_t)(2 * NT + r) * PADW, fcnt + 2 * NT + r);
        }
        return;
    }
    w -= 3 * NT;                         // ---- es: w in [0, 6912) ----
    es_task(w, lane, e0, e1, e2, part);
}

// ---------------------------------------------------------------- main: R10 version verbatim
__global__ __launch_bounds__(256)
void main_kernel(const float2* __restrict__ fjvL, const int* __restrict__ fcnt,
                 const float* __restrict__ partL, int nch,
                 const float* __restrict__ thr, const float* __restrict__ lt,
                 const float* __restrict__ resp,
                 float* __restrict__ out, int colOff) {
    int n = blockIdx.x;
    int tid = threadIdx.x;
    __shared__ float4 s_jv[TDEPTH][PADW / 2];   // (joff,v,joff,v) x 32 per tree
    __shared__ float2 s_resp2[DD][33];          // row stride 66 floats: 2-way alias only
    __shared__ float  s_ess[TDEPTH][DD];
    __shared__ float  s_thr[TDEPTH], s_elt[TDEPTH];
    __shared__ int    s_cnt[TDEPTH];

    {   // stage jv: 192 contiguous float4 for rows n*6..n*6+5
        const float4* g = (const float4*)(fjvL + (size_t)n * TDEPTH * PADW);
        if (tid < 192) ((float4*)s_jv)[tid] = g[tid];
    }
    {   // stage resp: 1024 float2
        const float2* g = (const float2*)(resp + (size_t)n * (DD * 64));
        for (int i = tid; i < DD * 32; i += 256)
            s_resp2[i >> 5][i & 31] = g[i];
    }
    if (tid < TDEPTH * DD) {             // 192 threads: ess chunk-sum (deterministic)
        int t = tid >> 5, d = tid & 31;
        float e = 0.f;
        #pragma unroll
        for (int c = 0; c < 5; ++c)
            if (c < nch) e += partL[((size_t)(n * TDEPTH + t) * 5 + c) * 32 + d];
        s_ess[t][d] = e;
    }
    if (tid < TDEPTH) {
        int r = n * TDEPTH + tid;
        s_thr[tid] = thr[r];
        s_elt[tid] = expf(-lt[r]);
        s_cnt[tid] = fcnt[r];
    }
    __syncthreads();

    int b = blockIdx.y * 8 + (tid >> 5);   // 0..63
    int d = tid & 31;
    const char* xbd = (const char*)(out + (size_t)b * OUT_STRIDE + d);  // +joff bytes = x[b][j][d]

    int maxc = s_cnt[0];
    #pragma unroll
    for (int t = 1; t < TDEPTH; ++t) maxc = max(maxc, s_cnt[t]);
    int rounds = (maxc + 7) >> 3;          // 8 pairs (4 float4) per tree per round

    float acc0 = 0.f, acc1 = 0.f, acc2 = 0.f, acc3 = 0.f, acc4 = 0.f, acc5 = 0.f;
    for (int r = 0; r < rounds; ++r) {
        int p4 = r * 4;
        #pragma unroll
        for (int t = 0; t < TDEPTH; ++t) {
            float4 q0 = s_jv[t][p4 + 0];
            float4 q1 = s_jv[t][p4 + 1];
            float4 q2 = s_jv[t][p4 + 2];
            float4 q3 = s_jv[t][p4 + 3];
            float x0 = *(const float*)(xbd + __float_as_int(q0.x));
            float x1 = *(const float*)(xbd + __float_as_int(q0.z));
            float x2 = *(const float*)(xbd + __float_as_int(q1.x));
            float x3 = *(const float*)(xbd + __float_as_int(q1.z));
            float x4 = *(const float*)(xbd + __float_as_int(q2.x));
            float x5 = *(const float*)(xbd + __float_as_int(q2.z));
            float x6 = *(const float*)(xbd + __float_as_int(q3.x));
            float x7 = *(const float*)(xbd + __float_as_int(q3.z));
            float a = ((x0 * q0.y + x1 * q0.w) + (x2 * q1.y + x3 * q1.w))
                    + ((x4 * q2.y + x5 * q2.w) + (x6 * q3.y + x7 * q3.w));
            if (t == 0) acc0 += a;
            if (t == 1) acc1 += a;
            if (t == 2) acc2 += a;
            if (t == 3) acc3 += a;
            if (t == 4) acc4 += a;
            if (t == 5) acc5 += a;
        }
    }
    float sv[TDEPTH];
    {
        float accs[TDEPTH] = {acc0, acc1, acc2, acc3, acc4, acc5};
        #pragma unroll
        for (int t = 0; t < TDEPTH; ++t) {
            float sel = accs[t] * s_ess[t][d];
            float tlv = (sel - s_thr[t]) * s_elt[t];
            sv[t] = fminf(fmaxf(0.5f * tlv + 0.5f, 0.f), 1.f);
        }
    }

    // A[c1]: trees 0-2 (bit i of c1 set => (1-sv[i])); B[c2]: trees 3-5
    float A[8], Bv[8];
    {
        float a0 = sv[0], a1 = 1.f - sv[0];
        float b0 = sv[1], b1 = 1.f - sv[1];
        float c0 = sv[2], c1 = 1.f - sv[2];
        A[0] = a0 * b0 * c0; A[1] = a1 * b0 * c0;
        A[2] = a0 * b1 * c0; A[3] = a1 * b1 * c0;
        A[4] = a0 * b0 * c1; A[5] = a1 * b0 * c1;
        A[6] = a0 * b1 * c1; A[7] = a1 * b1 * c1;
        float d0 = sv[3], d1 = 1.f - sv[3];
        float e0 = sv[4], e1 = 1.f - sv[4];
        float f0 = sv[5], f1 = 1.f - sv[5];
        Bv[0] = d0 * e0 * f0; Bv[1] = d1 * e0 * f0;
        Bv[2] = d0 * e1 * f0; Bv[3] = d1 * e1 * f0;
        Bv[4] = d0 * e0 * f1; Bv[5] = d1 * e0 * f1;
        Bv[6] = d0 * e1 * f1; Bv[7] = d1 * e1 * f1;
    }
    float o = 0.f;
    #pragma unroll
    for (int c2 = 0; c2 < 8; ++c2) {
        float2 r0 = s_resp2[d][(8 * c2) >> 1];
        float2 r1 = s_resp2[d][(8 * c2 + 2) >> 1];
        float2 r2 = s_resp2[d][(8 * c2 + 4) >> 1];
        float2 r3 = s_resp2[d][(8 * c2 + 6) >> 1];
        float inner = (A[0] * r0.x + A[1] * r0.y) + (A[2] * r1.x + A[3] * r1.y)
                    + (A[4] * r2.x + A[5] * r2.y) + (A[6] * r3.x + A[7] * r3.y);
        o += Bv[c2] * inner;
    }
    out[(size_t)b * OUT_STRIDE + (size_t)(colOff + n) * DD + d] = o;
}

// ----------------------------------------------------------------
extern "C" void kernel_launch(void* const* d_in, const int* in_sizes, int n_in,
                              void* d_out, int out_size, void* d_ws, size_t ws_size,
                              hipStream_t stream) {
    const float* x = (const float*)d_in[0];
    float* out = (float*)d_out;

    const size_t NPAD = (size_t)3 * NT * PADW;   // 147456 pairs
    char* ws = (char*)d_ws;
    float2* fjv  = (float2*)(ws);                         // 1.18 MB
    int*    fcnt = (int*)(ws + NPAD * 8);
    float*  part = (float*)(ws + NPAD * 8 + 16384);       // [3*NT][5][32]

    // 512 copy + 2304 fs + 6912 es = 9728 wave-tasks, 4 waves/block
    prep_kernel<<<9728 / 4, 256, 0, stream>>>(
        x,
        (const float*)d_in[1], (const float*)d_in[6], (const float*)d_in[11],
        (const float*)d_in[2], (const float*)d_in[7], (const float*)d_in[12],
        fjv, fcnt, part, out);

    const int nchs[3] = {1, 3, 5};
    int colOff = 64;
    for (int L = 0; L < 3; ++L) {
        const float* thr  = (const float*)d_in[3 + 5 * L];
        const float* lt   = (const float*)d_in[4 + 5 * L];
        const float* resp = (const float*)d_in[5 + 5 * L];
        main_kernel<<<dim3(NTREES, 8), 256, 0, stream>>>(
            fjv + (size_t)L * NT * PADW, fcnt + L * NT,
            part + (size_t)L * NT * 5 * 32, nchs[L],
            thr, lt, resp, out, colOff);
        colOff += NTREES;
    }
}

// Round 16
// 56.015 us; speedup vs baseline: 6.0331x; 1.1220x over previous
//
#include <hip/hip_runtime.h>

#define OUT_COLS 448
#define OUT_STRIDE (OUT_COLS * 32)   // 14336 floats per batch row
#define NTREES 128
#define TDEPTH 6
#define NT (NTREES * TDEPTH)         // 768 rows per layer
#define DD 32
#define BB 64
#define PADW 64                      // padded compacted width for fs output

// DPP mov helper (compile-time ctrl)
template <int CTRL, int RMASK = 0xf, bool BC = true>
__device__ __forceinline__ float dppf(float v) {
    return __int_as_float(
        __builtin_amdgcn_update_dpp(0, __float_as_int(v), CTRL, RMASK, 0xf, BC));
}

// full-wave (64-lane) sum, result broadcast to all lanes via readlane
__device__ __forceinline__ float wred64(float x) {
    x += dppf<0x111>(x);
    x += dppf<0x112>(x);
    x += dppf<0x114>(x);
    x += dppf<0x118>(x);
    x += __int_as_float(__builtin_amdgcn_update_dpp(0, __float_as_int(x), 0x142, 0xa, 0xf, false)); // row_bcast15
    x += __int_as_float(__builtin_amdgcn_update_dpp(0, __float_as_int(x), 0x143, 0xc, 0xf, false)); // row_bcast31
    return __int_as_float(__builtin_amdgcn_readlane(__float_as_int(x), 63));
}

// ---------------------------------------------------------------- fs sparsemax via Michelot (one wave/row)
// Output: interleaved (byte-offset, value) float2 pairs, zero-padded to PADW.
template <int J>
__device__ __forceinline__ void fs_row(const float* __restrict__ zr, int lane,
                                       float2* __restrict__ fjv, int* __restrict__ fcnt_p) {
    constexpr int T = J / 64;
    float z[T];
    #pragma unroll
    for (int t = 0; t < T; ++t) z[t] = zr[t * 64 + lane];
    float sp = 0.f;
    #pragma unroll
    for (int t = 0; t < T; ++t) sp += z[t];
    float k = (float)J;
    float tau = (wred64(sp) - 1.f) / k;
    #pragma unroll 1
    for (int it = 0; it < 64; ++it) {
        float s2 = 0.f, c2 = 0.f;
        #pragma unroll
        for (int t = 0; t < T; ++t) {
            bool g = z[t] > tau;
            s2 += g ? z[t] : 0.f;
            c2 += g ? 1.f : 0.f;
        }
        float S2 = wred64(s2);
        float K2 = wred64(c2);
        if (K2 == k) break;
        k = K2;
        tau = (S2 - 1.f) / K2;
    }
    unsigned long long below = (1ull << lane) - 1ull;
    int base = 0;
    #pragma unroll
    for (int t = 0; t < T; ++t) {
        bool sup = z[t] > tau;
        unsigned long long m = __ballot(sup);
        int pos = base + __popcll(m & below);
        if (sup && pos < PADW)
            fjv[pos] = make_float2(__int_as_float((t * 64 + lane) * 128), z[t] - tau);
        base += __popcll(m);
    }
    int cnt = base < PADW ? base : PADW;
    for (int i = cnt + lane; i < PADW; i += 64)
        fjv[i] = make_float2(__int_as_float(0), 0.f);
    if (lane == 0) *fcnt_p = cnt;
}

// butterfly exchange step S (xor 1<<S within 32 lanes) for es transpose-reduce
template <int S>
__device__ __forceinline__ void bstep(float* a, int lane) {
    constexpr int half = 16 >> S;
    bool up = ((lane >> S) & 1) != 0;
    #pragma unroll
    for (int q = 0; q < half; ++q) {
        float send = up ? a[q] : a[half + q];
        float recv;
        if constexpr (S == 0)      recv = dppf<0xB1>(send);
        else if constexpr (S == 1) recv = dppf<0x4E>(send);
        else recv = __int_as_float(__builtin_amdgcn_ds_swizzle(
                        __float_as_int(send), ((1 << S) << 10) | 0x1F));
        float keep = up ? a[half + q] : a[q];
        a[q] = keep + recv;
    }
}

// ---------------------------------------------------------------- fused prep: copy_x + fs + es
__global__ __launch_bounds__(256)
void prep_kernel(const float* __restrict__ x,
                 const float* __restrict__ f0, const float* __restrict__ f1,
                 const float* __restrict__ f2,
                 const float* __restrict__ e0, const float* __restrict__ e1,
                 const float* __restrict__ e2,
                 float2* __restrict__ fjv, int* __restrict__ fcnt,
                 float* __restrict__ part, float* __restrict__ out) {
    int w = blockIdx.x * 4 + (threadIdx.x >> 6);
    int lane = threadIdx.x & 63;

    if (w < 512) {                       // ---- copy x ----
        const float4* x4 = (const float4*)x;
        float4* o4 = (float4*)out;
        int g = w * 64 + lane;
        int b = g >> 9, r = g & 511;
        o4[(size_t)b * (OUT_STRIDE / 4) + r] = x4[g];
        return;
    }
    w -= 512;
    if (w < 3 * NT) {                    // ---- fs ----
        if (w < NT) {
            fs_row<64>(f0 + (size_t)w * 64, lane, fjv + (size_t)w * PADW, fcnt + w);
        } else if (w < 2 * NT) {
            int r = w - NT;
            fs_row<192>(f1 + (size_t)r * 192, lane,
                        fjv + (size_t)(NT + r) * PADW, fcnt + NT + r);
        } else {
            int r = w - 2 * NT;
            fs_row<320>(f2 + (size_t)r * 320, lane,
                        fjv + (size_t)(2 * NT + r) * PADW, fcnt + 2 * NT + r);
        }
        return;
    }
    w -= 3 * NT;                         // ---- es: w in [0, 6912) ----
    const float* esl; int row, chunk, J; size_t grow;
    if (w < NT)          { esl = e0; row = w; chunk = 0; J = 64; grow = (size_t)row; }
    else if (w < 4 * NT) { int q = w - NT; esl = e1; row = q / 3; chunk = q - row * 3; J = 192; grow = (size_t)(NT + row); }
    else                 { int q = w - 4 * NT; esl = e2; row = q / 5; chunk = q - row * 5; J = 320; grow = (size_t)(2 * NT + row); }

    const float4* zp4 = (const float4*)(esl + ((size_t)row * J + chunk * 64 + lane) * 32);
    float z[32];
    #pragma unroll
    for (int i = 0; i < 8; ++i) {
        float4 v = zp4[i];
        z[4 * i] = v.x; z[4 * i + 1] = v.y; z[4 * i + 2] = v.z; z[4 * i + 3] = v.w;
    }
    float mx = z[0];
    #pragma unroll
    for (int i = 1; i < 32; ++i) mx = fmaxf(mx, z[i]);
    float tau = mx - 1.0f;               // warm start (valid lower bound on tau*)
    int kprev = -1;
    #pragma unroll 1
    for (int it = 0; it < 40; ++it) {
        float s0 = 0.f, s1 = 0.f, s2 = 0.f, s3 = 0.f;
        int k0 = 0, k1 = 0, k2 = 0, k3 = 0;
        #pragma unroll
        for (int i = 0; i < 8; ++i) {
            bool g0 = z[4 * i]     > tau; s0 += g0 ? z[4 * i]     : 0.f; k0 += g0;
            bool g1 = z[4 * i + 1] > tau; s1 += g1 ? z[4 * i + 1] : 0.f; k1 += g1;
            bool g2 = z[4 * i + 2] > tau; s2 += g2 ? z[4 * i + 2] : 0.f; k2 += g2;
            bool g3 = z[4 * i + 3] > tau; s3 += g3 ? z[4 * i + 3] : 0.f; k3 += g3;
        }
        float S = (s0 + s1) + (s2 + s3);
        int k = (k0 + k1) + (k2 + k3);
        bool chg = (k != kprev);
        kprev = k;
        tau = (S - 1.0f) / (float)k;
        if (__ballot(chg) == 0ull) break;
    }
    #pragma unroll
    for (int i = 0; i < 32; ++i) z[i] = fmaxf(z[i] - tau, 0.f);
    bstep<0>(z, lane);
    bstep<1>(z, lane);
    bstep<2>(z, lane);
    bstep<3>(z, lane);
    bstep<4>(z, lane);
    z[0] += __shfl_xor(z[0], 32, 64);
    if (lane < 32) {
        int d = ((lane & 1) << 4) | ((lane & 2) << 2) | (lane & 4)
              | ((lane & 8) >> 2) | ((lane & 16) >> 4);
        part[(grow * 5 + chunk) * 32 + d] = z[0];
    }
}

// ---------------------------------------------------------------- main: thread = (b,d), block = (n, 8 b's)
// (j,v) pairs packed in LDS float4 (2 pairs per ds_read_b128); resp dot via float2, stride 66.
__global__ __launch_bounds__(256)
void main_kernel(const float2* __restrict__ fjvL, const int* __restrict__ fcnt,
                 const float* __restrict__ partL, int nch,
                 const float* __restrict__ thr, const float* __restrict__ lt,
                 const float* __restrict__ resp,
                 float* __restrict__ out, int colOff) {
    int n = blockIdx.x;
    int tid = threadIdx.x;
    __shared__ float4 s_jv[TDEPTH][PADW / 2];   // (joff,v,joff,v) x 32 per tree
    __shared__ float2 s_resp2[DD][33];          // row stride 66 floats: 2-way alias only
    __shared__ float  s_ess[TDEPTH][DD];
    __shared__ float  s_thr[TDEPTH], s_elt[TDEPTH];
    __shared__ int    s_cnt[TDEPTH];

    {   // stage jv: 192 contiguous float4 for rows n*6..n*6+5
        const float4* g = (const float4*)(fjvL + (size_t)n * TDEPTH * PADW);
        if (tid < 192) ((float4*)s_jv)[tid] = g[tid];
    }
    {   // stage resp: 1024 float2
        const float2* g = (const float2*)(resp + (size_t)n * (DD * 64));
        for (int i = tid; i < DD * 32; i += 256)
            s_resp2[i >> 5][i & 31] = g[i];
    }
    if (tid < TDEPTH * DD) {             // 192 threads: ess chunk-sum (deterministic)
        int t = tid >> 5, d = tid & 31;
        float e = 0.f;
        #pragma unroll
        for (int c = 0; c < 5; ++c)
            if (c < nch) e += partL[((size_t)(n * TDEPTH + t) * 5 + c) * 32 + d];
        s_ess[t][d] = e;
    }
    if (tid < TDEPTH) {
        int r = n * TDEPTH + tid;
        s_thr[tid] = thr[r];
        s_elt[tid] = expf(-lt[r]);
        s_cnt[tid] = fcnt[r];
    }
    __syncthreads();

    int b = blockIdx.y * 8 + (tid >> 5);   // 0..63
    int d = tid & 31;
    const char* xbd = (const char*)(out + (size_t)b * OUT_STRIDE + d);  // +joff bytes = x[b][j][d]

    int maxc = s_cnt[0];
    #pragma unroll
    for (int t = 1; t < TDEPTH; ++t) maxc = max(maxc, s_cnt[t]);
    int rounds = (maxc + 7) >> 3;          // 8 pairs (4 float4) per tree per round

    float acc0 = 0.f, acc1 = 0.f, acc2 = 0.f, acc3 = 0.f, acc4 = 0.f, acc5 = 0.f;
    for (int r = 0; r < rounds; ++r) {
        int p4 = r * 4;
        #pragma unroll
        for (int t = 0; t < TDEPTH; ++t) {
            float4 q0 = s_jv[t][p4 + 0];
            float4 q1 = s_jv[t][p4 + 1];
            float4 q2 = s_jv[t][p4 + 2];
            float4 q3 = s_jv[t][p4 + 3];
            float x0 = *(const float*)(xbd + __float_as_int(q0.x));
            float x1 = *(const float*)(xbd + __float_as_int(q0.z));
            float x2 = *(const float*)(xbd + __float_as_int(q1.x));
            float x3 = *(const float*)(xbd + __float_as_int(q1.z));
            float x4 = *(const float*)(xbd + __float_as_int(q2.x));
            float x5 = *(const float*)(xbd + __float_as_int(q2.z));
            float x6 = *(const float*)(xbd + __float_as_int(q3.x));
            float x7 = *(const float*)(xbd + __float_as_int(q3.z));
            float a = ((x0 * q0.y + x1 * q0.w) + (x2 * q1.y + x3 * q1.w))
                    + ((x4 * q2.y + x5 * q2.w) + (x6 * q3.y + x7 * q3.w));
            if (t == 0) acc0 += a;
            if (t == 1) acc1 += a;
            if (t == 2) acc2 += a;
            if (t == 3) acc3 += a;
            if (t == 4) acc4 += a;
            if (t == 5) acc5 += a;
        }
    }
    float sv[TDEPTH];
    {
        float accs[TDEPTH] = {acc0, acc1, acc2, acc3, acc4, acc5};
        #pragma unroll
        for (int t = 0; t < TDEPTH; ++t) {
            float sel = accs[t] * s_ess[t][d];
            float tlv = (sel - s_thr[t]) * s_elt[t];
            sv[t] = fminf(fmaxf(0.5f * tlv + 0.5f, 0.f), 1.f);
        }
    }

    // A[c1]: trees 0-2 (bit i of c1 set => (1-sv[i])); B[c2]: trees 3-5
    float A[8], Bv[8];
    {
        float a0 = sv[0], a1 = 1.f - sv[0];
        float b0 = sv[1], b1 = 1.f - sv[1];
        float c0 = sv[2], c1 = 1.f - sv[2];
        A[0] = a0 * b0 * c0; A[1] = a1 * b0 * c0;
        A[2] = a0 * b1 * c0; A[3] = a1 * b1 * c0;
        A[4] = a0 * b0 * c1; A[5] = a1 * b0 * c1;
        A[6] = a0 * b1 * c1; A[7] = a1 * b1 * c1;
        float d0 = sv[3], d1 = 1.f - sv[3];
        float e0 = sv[4], e1 = 1.f - sv[4];
        float f0 = sv[5], f1 = 1.f - sv[5];
        Bv[0] = d0 * e0 * f0; Bv[1] = d1 * e0 * f0;
        Bv[2] = d0 * e1 * f0; Bv[3] = d1 * e1 * f0;
        Bv[4] = d0 * e0 * f1; Bv[5] = d1 * e0 * f1;
        Bv[6] = d0 * e1 * f1; Bv[7] = d1 * e1 * f1;
    }
    float o = 0.f;
    #pragma unroll
    for (int c2 = 0; c2 < 8; ++c2) {
        float2 r0 = s_resp2[d][(8 * c2) >> 1];
        float2 r1 = s_resp2[d][(8 * c2 + 2) >> 1];
        float2 r2 = s_resp2[d][(8 * c2 + 4) >> 1];
        float2 r3 = s_resp2[d][(8 * c2 + 6) >> 1];
        float inner = (A[0] * r0.x + A[1] * r0.y) + (A[2] * r1.x + A[3] * r1.y)
                    + (A[4] * r2.x + A[5] * r2.y) + (A[6] * r3.x + A[7] * r3.y);
        o += Bv[c2] * inner;
    }
    out[(size_t)b * OUT_STRIDE + (size_t)(colOff + n) * DD + d] = o;
}

// ----------------------------------------------------------------
extern "C" void kernel_launch(void* const* d_in, const int* in_sizes, int n_in,
                              void* d_out, int out_size, void* d_ws, size_t ws_size,
                              hipStream_t stream) {
    const float* x = (const float*)d_in[0];
    float* out = (float*)d_out;

    const size_t NPAD = (size_t)3 * NT * PADW;   // 147456 pairs
    char* ws = (char*)d_ws;
    float2* fjv  = (float2*)(ws);                         // 1.18 MB
    int*    fcnt = (int*)(ws + NPAD * 8);
    float*  part = (float*)(ws + NPAD * 8 + 16384);       // [3*NT][5][32]

    // 512 copy + 2304 fs + 6912 es = 9728 wave-tasks, 4 waves/block
    prep_kernel<<<9728 / 4, 256, 0, stream>>>(
        x,
        (const float*)d_in[1], (const float*)d_in[6], (const float*)d_in[11],
        (const float*)d_in[2], (const float*)d_in[7], (const float*)d_in[12],
        fjv, fcnt, part, out);

    const int nchs[3] = {1, 3, 5};
    int colOff = 64;
    for (int L = 0; L < 3; ++L) {
        const float* thr  = (const float*)d_in[3 + 5 * L];
        const float* lt   = (const float*)d_in[4 + 5 * L];
        const float* resp = (const float*)d_in[5 + 5 * L];
        main_kernel<<<dim3(NTREES, 8), 256, 0, stream>>>(
            fjv + (size_t)L * NT * PADW, fcnt + L * NT,
            part + (size_t)L * NT * 5 * 32, nchs[L],
            thr, lt, resp, out, colOff);
        colOff += NTREES;
    }
}